// Round 12
// baseline (4400.263 us; speedup 1.0000x reference)
//
#include <hip/hip_runtime.h>

typedef unsigned short u16;
typedef unsigned int   u32;
typedef __attribute__((ext_vector_type(8))) short short8;
typedef __attribute__((ext_vector_type(4))) float f32x4;

// ---------------- constants ----------------
constexpr int Dc   = 512;
constexpr int Lc   = 6;
constexpr int Bc   = 16;
constexpr int Sc   = 2048;
constexpr int Rc   = Sc * Bc;                 // 32768 rows (b-major: r = b*S + s)
constexpr float RATIO = 0.3535533905932738f;  // 1/64^0.25
constexpr float STABc = 1e-3f;
constexpr float EPSc  = 1e-5f;

// f32 pair -> packed 2x bf16 (RNE)
__device__ __forceinline__ u32 pk2(float lo, float hi) {
    u32 a = __float_as_uint(lo), b = __float_as_uint(hi);
    a = (a + 0x7FFFu + ((a >> 16) & 1u)) >> 16;
    b = (b + 0x7FFFu + ((b >> 16) & 1u)) & 0xFFFF0000u;
    return a | b;
}
__device__ __forceinline__ u16 f2bh(float f) {
    u32 u = __float_as_uint(f);
    return (u16)((u + 0x7FFFu + ((u >> 16) & 1u)) >> 16);
}
__device__ __forceinline__ float b2f(u16 u) { return __uint_as_float(((u32)u) << 16); }

// ---------------- sentinel (ws too small diagnostic) ----------------
__global__ __launch_bounds__(256)
void sentinel_kernel(float* O, int n4) {
    int i = blockIdx.x * 256 + threadIdx.x;
    if (i < n4) {
        float4 v = make_float4(12345.f, 12345.f, 12345.f, 12345.f);
        *reinterpret_cast<float4*>(O + (size_t)i * 4) = v;
    }
}

// ---------------- zero KV/KSUM ----------------
__global__ __launch_bounds__(256)
void zero_kernel(float* p, int n4) {
    int i = blockIdx.x * 256 + threadIdx.x;
    if (i < n4) {
        float4 z = make_float4(0.f, 0.f, 0.f, 0.f);
        *reinterpret_cast<float4*>(p + (size_t)i * 4) = z;
    }
}

// ---------------- XP = bf16(X + pos)  (b-major: pos is linear) ----------------
__global__ __launch_bounds__(256)
void xp_kernel(const float* __restrict__ X, const float* __restrict__ POS,
               u16* __restrict__ XP) {
    size_t i = (size_t)blockIdx.x * 256 + threadIdx.x;   // 8-elem chunk
    size_t base = i * 8;
    float4 x0 = *reinterpret_cast<const float4*>(X + base);
    float4 x1 = *reinterpret_cast<const float4*>(X + base + 4);
    float4 p0 = *reinterpret_cast<const float4*>(POS + base);
    float4 p1 = *reinterpret_cast<const float4*>(POS + base + 4);
    uint4 o;
    o.x = pk2(x0.x + p0.x, x0.y + p0.y);
    o.y = pk2(x0.z + p0.z, x0.w + p0.w);
    o.z = pk2(x1.x + p1.x, x1.y + p1.y);
    o.w = pk2(x1.z + p1.z, x1.w + p1.w);
    *reinterpret_cast<uint4*>(XP + base) = o;
}

// ---------------- Weff precompute (ORF folded; weights bf16, bias f32) ----------------
__global__ __launch_bounds__(256)
void weff_kernel(const float* __restrict__ Wqkv, const float* __restrict__ bqkv,
                 const float* __restrict__ worf,
                 u16* __restrict__ WeffQ, u16* __restrict__ WeffK,
                 float* __restrict__ beffQ, float* __restrict__ beffK) {
    __shared__ float wl[64][64];
    __shared__ float ql[64][68];
    __shared__ float kl[64][68];
    int cc = blockIdx.x, h = blockIdx.y;
    int tid = threadIdx.x;
    for (int i = tid; i < 4096; i += 256) wl[i >> 6][i & 63] = worf[i];
    for (int i = tid; i < 4096; i += 256) {
        int d = i >> 6, c = i & 63;
        ql[d][c] = Wqkv[(size_t)(h * 64 + d) * 512 + cc * 64 + c];
        kl[d][c] = Wqkv[(size_t)(512 + h * 64 + d) * 512 + cc * 64 + c];
    }
    __syncthreads();
    int m = tid >> 2, c0 = (tid & 3) * 16;
    float acc[16];
    #pragma unroll
    for (int j = 0; j < 16; ++j) acc[j] = 0.f;
    for (int d = 0; d < 64; ++d) {
        float wv = wl[m][d];
        #pragma unroll
        for (int j = 0; j < 16; ++j) acc[j] = fmaf(wv, ql[d][c0 + j], acc[j]);
    }
    for (int j = 0; j < 16; ++j)
        WeffQ[(size_t)(h * 64 + m) * 512 + cc * 64 + c0 + j] = f2bh(RATIO * acc[j]);
    #pragma unroll
    for (int j = 0; j < 16; ++j) acc[j] = 0.f;
    for (int d = 0; d < 64; ++d) {
        float wv = wl[m][d];
        #pragma unroll
        for (int j = 0; j < 16; ++j) acc[j] = fmaf(wv, kl[d][c0 + j], acc[j]);
    }
    for (int j = 0; j < 16; ++j)
        WeffK[(size_t)(h * 64 + m) * 512 + cc * 64 + c0 + j] = f2bh(RATIO * acc[j]);
    if (cc == 0 && tid < 64) {
        float bq = 0.f, bk = 0.f;
        for (int d = 0; d < 64; ++d) {
            bq = fmaf(wl[tid][d], bqkv[h * 64 + d], bq);
            bk = fmaf(wl[tid][d], bqkv[512 + h * 64 + d], bk);
        }
        beffQ[h * 64 + tid] = RATIO * bq;
        beffK[h * 64 + tid] = RATIO * bk;
    }
}

// ---------------- MFMA GEMM (round-7 proven core): C[r,n] = op( sum_k A[r,k]*W[n,k] ) ----------------
// 128x128 tile, 4 waves (2x2 of 64x64), BK=32, LDS row stride 40 shorts.
// A bf16 (ABF16) or f32 (converted during staging). W bf16 (WBF16) or f32.
// MODE 0:+bias->bf16  1:relu->bf16  4:relu+STAB->bf16  2:+bias+res(f32)->f32  3:C+=acc(f32)
// WDEN (QP GEMM): DEN[row*8+h] = sum_cols(v * ksum), post-epilogue v.
template <int MODE, bool ABF16, bool WBF16, bool WDEN>
__global__ __launch_bounds__(256)
void gemm_mfma(const void* __restrict__ Av, int lda,
               const void* __restrict__ Wv, int ldw,
               const float* __restrict__ bias, const float* __restrict__ res,
               void* __restrict__ Cv, int ldc, int K,
               const float* __restrict__ KSUM, float* __restrict__ DEN) {
    constexpr int LP = 40;
    constexpr bool CB16 = (MODE == 0 || MODE == 1 || MODE == 4);
    __shared__ short As[128 * LP];
    __shared__ short Bs[128 * LP];
    int tid = threadIdx.x;
    int lane = tid & 63, wv = tid >> 6;
    int wr = wv >> 1, wc = wv & 1;
    int row0 = blockIdx.y * 128, col0 = blockIdx.x * 128;

    int srow = tid >> 1;
    int sks  = (tid & 1) << 4;              // 0 or 16
    int arow = row0 + srow;

    f32x4 acc[4][4];
    #pragma unroll
    for (int mi = 0; mi < 4; ++mi)
        #pragma unroll
        for (int ni = 0; ni < 4; ++ni)
            acc[mi][ni] = (f32x4){0.f, 0.f, 0.f, 0.f};

    int rl = lane & 15;
    int kg = (lane >> 4) * 8;

    for (int k0 = 0; k0 < K; k0 += 32) {
        uint4 qa0, qa1, qb0, qb1;
        if (ABF16) {
            const u16* Ap = (const u16*)Av + (size_t)arow * lda + sks;
            qa0 = *reinterpret_cast<const uint4*>(Ap + k0);
            qa1 = *reinterpret_cast<const uint4*>(Ap + k0 + 8);
        } else {
            const float* Ap = (const float*)Av + (size_t)arow * lda + sks;
            float4 a0 = *reinterpret_cast<const float4*>(Ap + k0);
            float4 a1 = *reinterpret_cast<const float4*>(Ap + k0 + 4);
            float4 a2 = *reinterpret_cast<const float4*>(Ap + k0 + 8);
            float4 a3 = *reinterpret_cast<const float4*>(Ap + k0 + 12);
            qa0.x = pk2(a0.x, a0.y); qa0.y = pk2(a0.z, a0.w);
            qa0.z = pk2(a1.x, a1.y); qa0.w = pk2(a1.z, a1.w);
            qa1.x = pk2(a2.x, a2.y); qa1.y = pk2(a2.z, a2.w);
            qa1.z = pk2(a3.x, a3.y); qa1.w = pk2(a3.z, a3.w);
        }
        if (WBF16) {
            const u16* Wp = (const u16*)Wv + (size_t)(col0 + srow) * ldw + sks;
            qb0 = *reinterpret_cast<const uint4*>(Wp + k0);
            qb1 = *reinterpret_cast<const uint4*>(Wp + k0 + 8);
        } else {
            const float* Wp = (const float*)Wv + (size_t)(col0 + srow) * ldw + sks;
            float4 b0 = *reinterpret_cast<const float4*>(Wp + k0);
            float4 b1 = *reinterpret_cast<const float4*>(Wp + k0 + 4);
            float4 b2 = *reinterpret_cast<const float4*>(Wp + k0 + 8);
            float4 b3 = *reinterpret_cast<const float4*>(Wp + k0 + 12);
            qb0.x = pk2(b0.x, b0.y); qb0.y = pk2(b0.z, b0.w);
            qb0.z = pk2(b1.x, b1.y); qb0.w = pk2(b1.z, b1.w);
            qb1.x = pk2(b2.x, b2.y); qb1.y = pk2(b2.z, b2.w);
            qb1.z = pk2(b3.x, b3.y); qb1.w = pk2(b3.z, b3.w);
        }
        __syncthreads();
        *reinterpret_cast<uint4*>(&As[srow * LP + sks])     = qa0;
        *reinterpret_cast<uint4*>(&As[srow * LP + sks + 8]) = qa1;
        *reinterpret_cast<uint4*>(&Bs[srow * LP + sks])     = qb0;
        *reinterpret_cast<uint4*>(&Bs[srow * LP + sks + 8]) = qb1;
        __syncthreads();
        short8 af[4], bf[4];
        #pragma unroll
        for (int mi = 0; mi < 4; ++mi)
            af[mi] = *reinterpret_cast<const short8*>(&As[(wr * 64 + mi * 16 + rl) * LP + kg]);
        #pragma unroll
        for (int ni = 0; ni < 4; ++ni)
            bf[ni] = *reinterpret_cast<const short8*>(&Bs[(wc * 64 + ni * 16 + rl) * LP + kg]);
        #pragma unroll
        for (int mi = 0; mi < 4; ++mi)
            #pragma unroll
            for (int ni = 0; ni < 4; ++ni)
                acc[mi][ni] = __builtin_amdgcn_mfma_f32_16x16x32_bf16(
                    af[mi], bf[ni], acc[mi][ni], 0, 0, 0);
    }

    int orb = row0 + wr * 64 + (lane >> 4) * 4;
    int ocb = col0 + wc * 64 + rl;
    float bv[4], ks4[4];
    int hh = (col0 + wc * 64) >> 6;
    #pragma unroll
    for (int ni = 0; ni < 4; ++ni) {
        bv[ni] = (MODE != 3) ? bias[ocb + ni * 16] : 0.f;
        if (WDEN) ks4[ni] = KSUM[(size_t)((row0 >> 11) * 8 + hh) * 64 + ni * 16 + rl];
    }
    #pragma unroll
    for (int mi = 0; mi < 4; ++mi) {
        #pragma unroll
        for (int j = 0; j < 4; ++j) {
            int orow = orb + mi * 16 + j;
            size_t base = (size_t)orow * ldc + ocb;
            float p = 0.f;
            #pragma unroll
            for (int ni = 0; ni < 4; ++ni) {
                float v = acc[mi][ni][j] + bv[ni];
                if (MODE == 1) v = fmaxf(v, 0.f);
                if (MODE == 4) v = fmaxf(v, 0.f) + STABc;
                size_t off = base + ni * 16;
                if (MODE == 2) v += res[off];
                if (MODE == 3) v += ((float*)Cv)[off];
                if (CB16) ((u16*)Cv)[off] = f2bh(v);
                else      ((float*)Cv)[off] = v;
                if (WDEN) p = fmaf(v, ks4[ni], p);
            }
            if (WDEN) {
                p += __shfl_xor(p, 1);
                p += __shfl_xor(p, 2);
                p += __shfl_xor(p, 4);
                p += __shfl_xor(p, 8);
                if (rl == 0) DEN[(size_t)orow * 8 + hh] = p;
            }
        }
    }
}

// ---------------- kv split-K: grid(128 bh, 4 sc), atomics into zeroed KV/KSUM ----------------
__global__ __launch_bounds__(256)
void kv_split(const u16* __restrict__ KP, const u16* __restrict__ V,
              float* __restrict__ KV, float* __restrict__ KSUM) {
    __shared__ u16 kpl[128 * 64];
    __shared__ u16 vl[128 * 64];
    int bh = blockIdx.x, sc = blockIdx.y;
    int b = bh >> 3, h = bh & 7;
    int tid = threadIdx.x;
    int d = tid & 63, mg = tid >> 6;        // 4 m-groups of 16
    float acc[16], ks[16];
    #pragma unroll
    for (int i = 0; i < 16; ++i) { acc[i] = 0.f; ks[i] = 0.f; }
    size_t rowbase = (size_t)b * Sc + sc * 512;
    for (int c = 0; c < 4; ++c) {
        __syncthreads();
        for (int i = tid; i < 1024; i += 256) {
            int row = i >> 3, c8 = (i & 7) * 8;
            size_t off = (rowbase + c * 128 + row) * Dc + h * 64 + c8;
            *reinterpret_cast<uint4*>(&kpl[row * 64 + c8]) =
                *reinterpret_cast<const uint4*>(KP + off);
            *reinterpret_cast<uint4*>(&vl[row * 64 + c8]) =
                *reinterpret_cast<const uint4*>(V + off);
        }
        __syncthreads();
        for (int s = 0; s < 128; ++s) {
            float vv = b2f(vl[s * 64 + d]);
            #pragma unroll
            for (int i = 0; i < 16; ++i) {
                float kp = b2f(kpl[s * 64 + mg * 16 + i]);
                acc[i] = fmaf(kp, vv, acc[i]);
                ks[i] += kp;
            }
        }
    }
    float* kvp = KV + (size_t)bh * 4096;
    #pragma unroll
    for (int i = 0; i < 16; ++i)
        atomicAdd(&kvp[(mg * 16 + i) * 64 + d], acc[i]);
    if (d == 0) {
        #pragma unroll
        for (int i = 0; i < 16; ++i)
            atomicAdd(&KSUM[bh * 64 + mg * 16 + i], ks[i]);
    }
}

// ---------------- num/den via MFMA: AO[r,h*64+d] = (QP[r,:].KV[b,h][:,d]) / DEN[r,h] ----------------
__global__ __launch_bounds__(256)
void numden_mfma(const u16* __restrict__ QP, const float* __restrict__ KVg,
                 const float* __restrict__ DEN, u16* __restrict__ OUT) {
    constexpr int LP = 72;
    __shared__ short Asm[128 * LP];
    __shared__ short BT[64 * LP];
    int h  = blockIdx.x;                   // 0..7
    int row0 = blockIdx.y * 128;
    int b  = row0 >> 11;
    int tid = threadIdx.x;
    int lane = tid & 63, w = tid >> 6;

    const float* kvp = KVg + ((size_t)(b * 8 + h)) * 4096;
    for (int i = tid; i < 4096; i += 256) {
        int m = i >> 6, d = i & 63;
        BT[d * LP + m] = (short)f2bh(kvp[i]);
    }
    {
        int rr = tid >> 1;
        int cc = (tid & 1) * 32;
        const u16* qp = QP + (size_t)(row0 + rr) * Dc + h * 64 + cc;
        #pragma unroll
        for (int q = 0; q < 4; ++q)
            *reinterpret_cast<uint4*>(&Asm[rr * LP + cc + q * 8]) =
                *reinterpret_cast<const uint4*>(qp + q * 8);
    }
    __syncthreads();

    int rl = lane & 15, kq = (lane >> 4) * 8;
    f32x4 acc[2][4];
    #pragma unroll
    for (int mi = 0; mi < 2; ++mi)
        #pragma unroll
        for (int ni = 0; ni < 4; ++ni) acc[mi][ni] = (f32x4){0.f, 0.f, 0.f, 0.f};
    #pragma unroll
    for (int kst = 0; kst < 2; ++kst) {
        int kg = kst * 32 + kq;
        short8 a0 = *reinterpret_cast<const short8*>(&Asm[(w * 32 + rl) * LP + kg]);
        short8 a1 = *reinterpret_cast<const short8*>(&Asm[(w * 32 + 16 + rl) * LP + kg]);
        short8 bf[4];
        #pragma unroll
        for (int ni = 0; ni < 4; ++ni)
            bf[ni] = *reinterpret_cast<const short8*>(&BT[(ni * 16 + rl) * LP + kg]);
        #pragma unroll
        for (int ni = 0; ni < 4; ++ni) {
            acc[0][ni] = __builtin_amdgcn_mfma_f32_16x16x32_bf16(a0, bf[ni], acc[0][ni], 0, 0, 0);
            acc[1][ni] = __builtin_amdgcn_mfma_f32_16x16x32_bf16(a1, bf[ni], acc[1][ni], 0, 0, 0);
        }
    }
    #pragma unroll
    for (int mi = 0; mi < 2; ++mi) {
        #pragma unroll
        for (int j = 0; j < 4; ++j) {
            int row = row0 + w * 32 + mi * 16 + (lane >> 4) * 4 + j;
            float inv = 1.f / DEN[(size_t)row * 8 + h];
            #pragma unroll
            for (int ni = 0; ni < 4; ++ni)
                OUT[(size_t)row * Dc + h * 64 + ni * 16 + rl] =
                    f2bh(acc[mi][ni][j] * inv);
        }
    }
}

// ---------------- LayerNorm over D=512, wave per row; PERM: b-major -> [S,B,D] ----------------
template <bool PERM>
__global__ __launch_bounds__(256)
void ln_kernel(const float* __restrict__ X, const float* __restrict__ Sg,
               const float* __restrict__ Bg, float* __restrict__ O) {
    int lane = threadIdx.x & 63, w = threadIdx.x >> 6;
    size_t r = (size_t)blockIdx.x * 4 + w;
    const float* xr = X + r * Dc;
    float v[8];
    *reinterpret_cast<float4*>(&v[0]) = *reinterpret_cast<const float4*>(xr + lane * 4);
    *reinterpret_cast<float4*>(&v[4]) = *reinterpret_cast<const float4*>(xr + 256 + lane * 4);
    float sum = 0.f;
    #pragma unroll
    for (int i = 0; i < 8; ++i) sum += v[i];
    #pragma unroll
    for (int off = 32; off >= 1; off >>= 1) sum += __shfl_xor(sum, off);
    float mu = sum * (1.f / Dc);
    float sq = 0.f;
    #pragma unroll
    for (int i = 0; i < 8; ++i) { float dd = v[i] - mu; sq += dd * dd; }
    #pragma unroll
    for (int off = 32; off >= 1; off >>= 1) sq += __shfl_xor(sq, off);
    float rstd = rsqrtf(sq * (1.f / Dc) + EPSc);
    float s[8], b[8];
    *reinterpret_cast<float4*>(&s[0]) = *reinterpret_cast<const float4*>(Sg + lane * 4);
    *reinterpret_cast<float4*>(&s[4]) = *reinterpret_cast<const float4*>(Sg + 256 + lane * 4);
    *reinterpret_cast<float4*>(&b[0]) = *reinterpret_cast<const float4*>(Bg + lane * 4);
    *reinterpret_cast<float4*>(&b[4]) = *reinterpret_cast<const float4*>(Bg + 256 + lane * 4);
    float o[8];
    #pragma unroll
    for (int i = 0; i < 8; ++i) o[i] = (v[i] - mu) * rstd * s[i] + b[i];
    size_t rd = PERM ? ((size_t)(r & (Sc - 1)) * Bc + (r >> 11)) : r;
    float* orow = O + rd * Dc;
    *reinterpret_cast<float4*>(orow + lane * 4) = *reinterpret_cast<const float4*>(&o[0]);
    *reinterpret_cast<float4*>(orow + 256 + lane * 4) = *reinterpret_cast<const float4*>(&o[4]);
}

// ---------------- launch ----------------
extern "C" void kernel_launch(void* const* d_in, const int* in_sizes, int n_in,
                              void* d_out, int out_size, void* d_ws, size_t ws_size,
                              hipStream_t stream) {
    (void)in_sizes; (void)n_in; (void)out_size;
    const float* src   = (const float*)d_in[0];
    const float* pos   = (const float*)d_in[2];
    const float* ipw   = (const float*)d_in[3];   // [L,1536,512]
    const float* ipb   = (const float*)d_in[4];   // [L,1536]
    const float* outw  = (const float*)d_in[5];   // [L,512,512]
    const float* outb  = (const float*)d_in[6];
    const float* l1w   = (const float*)d_in[7];   // [L,2048,512]
    const float* l1b   = (const float*)d_in[8];
    const float* l2w   = (const float*)d_in[9];   // [L,512,2048]
    const float* l2b   = (const float*)d_in[10];
    const float* n1s   = (const float*)d_in[11];
    const float* n1b   = (const float*)d_in[12];
    const float* n2s   = (const float*)d_in[13];
    const float* n2b   = (const float*)d_in[14];
    const float* worf  = (const float*)d_in[15];  // [L,64,64]
    float* out = (float*)d_out;

    const size_t RD = (size_t)Rc * Dc;            // 16,777,216 elems
    // ws: X f32 | B2 f32 | KV f32 | KSUM | DEN | WeffQ/K bf16 | beffQ/K f32
    const size_t NEED = RD * 4 + RD * 4 + (size_t)128 * 4096 * 4 + 8192 * 4
                      + (size_t)Rc * 8 * 4 + 2 * 262144 * 2 + 2 * 512 * 4;  // 138,448,896 (proven)
    if (ws_size < NEED) {
        sentinel_kernel<<<(Rc * Dc / 4 + 255) / 256, 256, 0, stream>>>(out, Rc * Dc / 4);
        return;
    }
    char* p = (char*)d_ws;
    float* X    = (float*)p;  p += RD * 4;
    float* B2f  = (float*)p;  p += RD * 4;
    float* KV   = (float*)p;  p += (size_t)128 * 4096 * 4;
    float* KSUM = (float*)p;  p += 8192 * 4;
    float* DEN  = (float*)p;  p += (size_t)Rc * 8 * 4;
    u16*  WeffQ = (u16*)p;    p += 262144 * 2;
    u16*  WeffK = (u16*)p;    p += 262144 * 2;
    float* beffQ = (float*)p; p += 512 * 4;
    float* beffK = (float*)p;

    u16*  B2u  = (u16*)B2f;           // 2*RD u16 capacity
    u16*  XPu  = B2u;                 // [R,512] bf16
    u16*  KPu  = B2u + RD;            // [R,512] bf16
    u16*  AOu  = B2u + RD;            // (KP dead by then)
    u16*  H1u  = B2u;                 // [R,2048] bf16 contiguous (XP/AO dead)
    u16*  OutU = (u16*)out;
    u16*  Vu   = OutU;                // [R,512] bf16
    u16*  QPu  = OutU + RD;           // [R,512] bf16
    float* T1f = out;                 // f32 [R,512] (V/QP dead)

    dim3 blk(256);
    dim3 g512(4, Rc / 128);
    dim3 g2048(16, Rc / 128);
    const int nz4 = (128 * 4096 + 8192) / 4;   // KV+KSUM contiguous

    for (int i = 0; i < Lc; ++i) {
        const float* w_qkv = ipw + (size_t)i * 1536 * 512;
        const float* b_qkv = ipb + (size_t)i * 1536;
        const float* w_v  = w_qkv + (size_t)1024 * 512;
        const float* b_v  = b_qkv + 1024;
        const float* w_o  = outw + (size_t)i * 512 * 512;
        const float* b_o  = outb + (size_t)i * 512;
        const float* w_1  = l1w + (size_t)i * 2048 * 512;
        const float* b_1  = l1b + (size_t)i * 2048;
        const float* w_2  = l2w + (size_t)i * 512 * 2048;
        const float* b_2  = l2b + (size_t)i * 512;
        const float* wo_i = worf + (size_t)i * 4096;

        weff_kernel<<<dim3(8, 8), blk, 0, stream>>>(
            w_qkv, b_qkv, wo_i, WeffQ, WeffK, beffQ, beffK);

        if (i == 0)
            hipMemcpyAsync(X, src, RD * 4, hipMemcpyDeviceToDevice, stream);

        // XP = bf16(X + pos)
        xp_kernel<<<(int)(RD / 8 / 256), blk, 0, stream>>>(X, pos, XPu);
        // KP = relu(XP @ WeffK^T + beffK) + STAB -> bf16
        gemm_mfma<4, true, true, false><<<g512, blk, 0, stream>>>(
            XPu, 512, WeffK, 512, beffK, nullptr, KPu, 512, 512, nullptr, nullptr);
        // V = X @ Wv^T + bv -> bf16
        gemm_mfma<0, false, false, false><<<g512, blk, 0, stream>>>(
            X, 512, w_v, 512, b_v, nullptr, Vu, 512, 512, nullptr, nullptr);
        // zero KV+KSUM, then kv split-K
        zero_kernel<<<(nz4 + 255) / 256, blk, 0, stream>>>(KV, nz4);
        kv_split<<<dim3(128, 4), blk, 0, stream>>>(KPu, Vu, KV, KSUM);
        // QP (+DEN) -> bf16
        gemm_mfma<4, true, true, true><<<g512, blk, 0, stream>>>(
            XPu, 512, WeffQ, 512, beffQ, nullptr, QPu, 512, 512, KSUM, DEN);
        // AO = num/den -> bf16 (KP region dead)
        numden_mfma<<<dim3(8, Rc / 128), blk, 0, stream>>>(QPu, KV, DEN, AOu);
        // T1 = X + AO @ Wo^T + bo -> f32 in d_out (V/QP dead)
        gemm_mfma<2, true, false, false><<<g512, blk, 0, stream>>>(
            AOu, 512, w_o, 512, b_o, X, T1f, 512, 512, nullptr, nullptr);
        // x = LN(T1) -> X
        ln_kernel<false><<<Rc / 4, blk, 0, stream>>>(T1f, n1s + i * 512, n1b + i * 512, X);
        // FFN1: H1 = relu(X @ W1^T + b1) bf16, ONE N=2048 dispatch -> B2 (XP/AO dead)
        gemm_mfma<1, false, false, false><<<g2048, blk, 0, stream>>>(
            X, 512, w_1, 512, b_1, nullptr, H1u, 2048, 512, nullptr, nullptr);
        // FFN2: X = X + H1 @ W2^T + b2  (two K=1024 halves on contiguous H1, in-place f32)
        gemm_mfma<2, true, false, false><<<g512, blk, 0, stream>>>(
            H1u, 2048, w_2, 2048, b_2, X, X, 512, 1024, nullptr, nullptr);
        gemm_mfma<3, true, false, false><<<g512, blk, 0, stream>>>(
            H1u + 1024, 2048, w_2 + 1024, 2048, nullptr, nullptr, X, 512, 1024, nullptr, nullptr);
        // x = LN(T2=X); final layer permutes b-major -> [S,B,D] into d_out
        if (i == Lc - 1)
            ln_kernel<true><<<Rc / 4, blk, 0, stream>>>(X, n2s + i * 512, n2b + i * 512, out);
        else
            ln_kernel<false><<<Rc / 4, blk, 0, stream>>>(X, n2s + i * 512, n2b + i * 512, X);
    }
}

// Round 13
// 4154.927 us; speedup vs baseline: 1.0590x; 1.0590x over previous
//
#include <hip/hip_runtime.h>

typedef unsigned short u16;
typedef unsigned int   u32;
typedef __attribute__((ext_vector_type(8))) short short8;
typedef __attribute__((ext_vector_type(4))) float f32x4;

// ---------------- constants ----------------
constexpr int Dc   = 512;
constexpr int Lc   = 6;
constexpr int Bc   = 16;
constexpr int Sc   = 2048;
constexpr int Rc   = Sc * Bc;                 // 32768 rows (b-major: r = b*S + s)
constexpr float RATIO = 0.3535533905932738f;  // 1/64^0.25
constexpr float STABc = 1e-3f;
constexpr float EPSc  = 1e-5f;

// f32 pair -> packed 2x bf16 (RNE)
__device__ __forceinline__ u32 pk2(float lo, float hi) {
    u32 a = __float_as_uint(lo), b = __float_as_uint(hi);
    a = (a + 0x7FFFu + ((a >> 16) & 1u)) >> 16;
    b = (b + 0x7FFFu + ((b >> 16) & 1u)) & 0xFFFF0000u;
    return a | b;
}
__device__ __forceinline__ u16 f2bh(float f) {
    u32 u = __float_as_uint(f);
    return (u16)((u + 0x7FFFu + ((u >> 16) & 1u)) >> 16);
}
__device__ __forceinline__ float b2f(u16 u) { return __uint_as_float(((u32)u) << 16); }

// ---------------- sentinel (ws too small diagnostic) ----------------
__global__ __launch_bounds__(256)
void sentinel_kernel(float* O, int n4) {
    int i = blockIdx.x * 256 + threadIdx.x;
    if (i < n4) {
        float4 v = make_float4(12345.f, 12345.f, 12345.f, 12345.f);
        *reinterpret_cast<float4*>(O + (size_t)i * 4) = v;
    }
}

// ---------------- zero KV/KSUM ----------------
__global__ __launch_bounds__(256)
void zero_kernel(float* p, int n4) {
    int i = blockIdx.x * 256 + threadIdx.x;
    if (i < n4) {
        float4 z = make_float4(0.f, 0.f, 0.f, 0.f);
        *reinterpret_cast<float4*>(p + (size_t)i * 4) = z;
    }
}

// ---------------- XP = bf16(X + pos)  (b-major: pos is linear) ----------------
__global__ __launch_bounds__(256)
void xp_kernel(const float* __restrict__ X, const float* __restrict__ POS,
               u16* __restrict__ XP) {
    size_t i = (size_t)blockIdx.x * 256 + threadIdx.x;   // 8-elem chunk
    size_t base = i * 8;
    float4 x0 = *reinterpret_cast<const float4*>(X + base);
    float4 x1 = *reinterpret_cast<const float4*>(X + base + 4);
    float4 p0 = *reinterpret_cast<const float4*>(POS + base);
    float4 p1 = *reinterpret_cast<const float4*>(POS + base + 4);
    uint4 o;
    o.x = pk2(x0.x + p0.x, x0.y + p0.y);
    o.y = pk2(x0.z + p0.z, x0.w + p0.w);
    o.z = pk2(x1.x + p1.x, x1.y + p1.y);
    o.w = pk2(x1.z + p1.z, x1.w + p1.w);
    *reinterpret_cast<uint4*>(XP + base) = o;
}

// ---------------- XB = bf16(X)  (twin for bf16-A GEMMs) ----------------
__global__ __launch_bounds__(256)
void xb_kernel(const float* __restrict__ X, u16* __restrict__ XB) {
    size_t i = (size_t)blockIdx.x * 256 + threadIdx.x;   // 8-elem chunk
    size_t base = i * 8;
    float4 x0 = *reinterpret_cast<const float4*>(X + base);
    float4 x1 = *reinterpret_cast<const float4*>(X + base + 4);
    uint4 o;
    o.x = pk2(x0.x, x0.y); o.y = pk2(x0.z, x0.w);
    o.z = pk2(x1.x, x1.y); o.w = pk2(x1.z, x1.w);
    *reinterpret_cast<uint4*>(XB + base) = o;
}

// ---------------- Weff precompute (ORF folded; weights bf16, bias f32) ----------------
__global__ __launch_bounds__(256)
void weff_kernel(const float* __restrict__ Wqkv, const float* __restrict__ bqkv,
                 const float* __restrict__ worf,
                 u16* __restrict__ WeffQ, u16* __restrict__ WeffK,
                 float* __restrict__ beffQ, float* __restrict__ beffK) {
    __shared__ float wl[64][64];
    __shared__ float ql[64][68];
    __shared__ float kl[64][68];
    int cc = blockIdx.x, h = blockIdx.y;
    int tid = threadIdx.x;
    for (int i = tid; i < 4096; i += 256) wl[i >> 6][i & 63] = worf[i];
    for (int i = tid; i < 4096; i += 256) {
        int d = i >> 6, c = i & 63;
        ql[d][c] = Wqkv[(size_t)(h * 64 + d) * 512 + cc * 64 + c];
        kl[d][c] = Wqkv[(size_t)(512 + h * 64 + d) * 512 + cc * 64 + c];
    }
    __syncthreads();
    int m = tid >> 2, c0 = (tid & 3) * 16;
    float acc[16];
    #pragma unroll
    for (int j = 0; j < 16; ++j) acc[j] = 0.f;
    for (int d = 0; d < 64; ++d) {
        float wv = wl[m][d];
        #pragma unroll
        for (int j = 0; j < 16; ++j) acc[j] = fmaf(wv, ql[d][c0 + j], acc[j]);
    }
    for (int j = 0; j < 16; ++j)
        WeffQ[(size_t)(h * 64 + m) * 512 + cc * 64 + c0 + j] = f2bh(RATIO * acc[j]);
    #pragma unroll
    for (int j = 0; j < 16; ++j) acc[j] = 0.f;
    for (int d = 0; d < 64; ++d) {
        float wv = wl[m][d];
        #pragma unroll
        for (int j = 0; j < 16; ++j) acc[j] = fmaf(wv, kl[d][c0 + j], acc[j]);
    }
    for (int j = 0; j < 16; ++j)
        WeffK[(size_t)(h * 64 + m) * 512 + cc * 64 + c0 + j] = f2bh(RATIO * acc[j]);
    if (cc == 0 && tid < 64) {
        float bq = 0.f, bk = 0.f;
        for (int d = 0; d < 64; ++d) {
            bq = fmaf(wl[tid][d], bqkv[h * 64 + d], bq);
            bk = fmaf(wl[tid][d], bqkv[512 + h * 64 + d], bk);
        }
        beffQ[h * 64 + tid] = RATIO * bq;
        beffK[h * 64 + tid] = RATIO * bk;
    }
}

// ---------------- MFMA GEMM (round-7 proven core): C[r,n] = op( sum_k A[r,k]*W[n,k] ) ----------------
// 128x128 tile, 4 waves (2x2 of 64x64), BK=32, LDS row stride 40 shorts.
// A bf16 (ABF16) or f32 (converted during staging). W bf16 (WBF16) or f32.
// MODE 0:+bias->bf16  1:relu->bf16  4:relu+STAB->bf16  2:+bias+res(f32)->f32  3:C+=acc(f32)
// WDEN (QP GEMM): DEN[row*8+h] = sum_cols(v * ksum), post-epilogue v.
template <int MODE, bool ABF16, bool WBF16, bool WDEN>
__global__ __launch_bounds__(256)
void gemm_mfma(const void* __restrict__ Av, int lda,
               const void* __restrict__ Wv, int ldw,
               const float* __restrict__ bias, const float* __restrict__ res,
               void* __restrict__ Cv, int ldc, int K,
               const float* __restrict__ KSUM, float* __restrict__ DEN) {
    constexpr int LP = 40;
    constexpr bool CB16 = (MODE == 0 || MODE == 1 || MODE == 4);
    __shared__ short As[128 * LP];
    __shared__ short Bs[128 * LP];
    int tid = threadIdx.x;
    int lane = tid & 63, wv = tid >> 6;
    int wr = wv >> 1, wc = wv & 1;
    int row0 = blockIdx.y * 128, col0 = blockIdx.x * 128;

    int srow = tid >> 1;
    int sks  = (tid & 1) << 4;              // 0 or 16
    int arow = row0 + srow;

    f32x4 acc[4][4];
    #pragma unroll
    for (int mi = 0; mi < 4; ++mi)
        #pragma unroll
        for (int ni = 0; ni < 4; ++ni)
            acc[mi][ni] = (f32x4){0.f, 0.f, 0.f, 0.f};

    int rl = lane & 15;
    int kg = (lane >> 4) * 8;

    for (int k0 = 0; k0 < K; k0 += 32) {
        uint4 qa0, qa1, qb0, qb1;
        if (ABF16) {
            const u16* Ap = (const u16*)Av + (size_t)arow * lda + sks;
            qa0 = *reinterpret_cast<const uint4*>(Ap + k0);
            qa1 = *reinterpret_cast<const uint4*>(Ap + k0 + 8);
        } else {
            const float* Ap = (const float*)Av + (size_t)arow * lda + sks;
            float4 a0 = *reinterpret_cast<const float4*>(Ap + k0);
            float4 a1 = *reinterpret_cast<const float4*>(Ap + k0 + 4);
            float4 a2 = *reinterpret_cast<const float4*>(Ap + k0 + 8);
            float4 a3 = *reinterpret_cast<const float4*>(Ap + k0 + 12);
            qa0.x = pk2(a0.x, a0.y); qa0.y = pk2(a0.z, a0.w);
            qa0.z = pk2(a1.x, a1.y); qa0.w = pk2(a1.z, a1.w);
            qa1.x = pk2(a2.x, a2.y); qa1.y = pk2(a2.z, a2.w);
            qa1.z = pk2(a3.x, a3.y); qa1.w = pk2(a3.z, a3.w);
        }
        if (WBF16) {
            const u16* Wp = (const u16*)Wv + (size_t)(col0 + srow) * ldw + sks;
            qb0 = *reinterpret_cast<const uint4*>(Wp + k0);
            qb1 = *reinterpret_cast<const uint4*>(Wp + k0 + 8);
        } else {
            const float* Wp = (const float*)Wv + (size_t)(col0 + srow) * ldw + sks;
            float4 b0 = *reinterpret_cast<const float4*>(Wp + k0);
            float4 b1 = *reinterpret_cast<const float4*>(Wp + k0 + 4);
            float4 b2 = *reinterpret_cast<const float4*>(Wp + k0 + 8);
            float4 b3 = *reinterpret_cast<const float4*>(Wp + k0 + 12);
            qb0.x = pk2(b0.x, b0.y); qb0.y = pk2(b0.z, b0.w);
            qb0.z = pk2(b1.x, b1.y); qb0.w = pk2(b1.z, b1.w);
            qb1.x = pk2(b2.x, b2.y); qb1.y = pk2(b2.z, b2.w);
            qb1.z = pk2(b3.x, b3.y); qb1.w = pk2(b3.z, b3.w);
        }
        __syncthreads();
        *reinterpret_cast<uint4*>(&As[srow * LP + sks])     = qa0;
        *reinterpret_cast<uint4*>(&As[srow * LP + sks + 8]) = qa1;
        *reinterpret_cast<uint4*>(&Bs[srow * LP + sks])     = qb0;
        *reinterpret_cast<uint4*>(&Bs[srow * LP + sks + 8]) = qb1;
        __syncthreads();
        short8 af[4], bf[4];
        #pragma unroll
        for (int mi = 0; mi < 4; ++mi)
            af[mi] = *reinterpret_cast<const short8*>(&As[(wr * 64 + mi * 16 + rl) * LP + kg]);
        #pragma unroll
        for (int ni = 0; ni < 4; ++ni)
            bf[ni] = *reinterpret_cast<const short8*>(&Bs[(wc * 64 + ni * 16 + rl) * LP + kg]);
        #pragma unroll
        for (int mi = 0; mi < 4; ++mi)
            #pragma unroll
            for (int ni = 0; ni < 4; ++ni)
                acc[mi][ni] = __builtin_amdgcn_mfma_f32_16x16x32_bf16(
                    af[mi], bf[ni], acc[mi][ni], 0, 0, 0);
    }

    int orb = row0 + wr * 64 + (lane >> 4) * 4;
    int ocb = col0 + wc * 64 + rl;
    float bv[4], ks4[4];
    int hh = (col0 + wc * 64) >> 6;
    #pragma unroll
    for (int ni = 0; ni < 4; ++ni) {
        bv[ni] = (MODE != 3) ? bias[ocb + ni * 16] : 0.f;
        if (WDEN) ks4[ni] = KSUM[(size_t)((row0 >> 11) * 8 + hh) * 64 + ni * 16 + rl];
    }
    #pragma unroll
    for (int mi = 0; mi < 4; ++mi) {
        #pragma unroll
        for (int j = 0; j < 4; ++j) {
            int orow = orb + mi * 16 + j;
            size_t base = (size_t)orow * ldc + ocb;
            float p = 0.f;
            #pragma unroll
            for (int ni = 0; ni < 4; ++ni) {
                float v = acc[mi][ni][j] + bv[ni];
                if (MODE == 1) v = fmaxf(v, 0.f);
                if (MODE == 4) v = fmaxf(v, 0.f) + STABc;
                size_t off = base + ni * 16;
                if (MODE == 2) v += res[off];
                if (MODE == 3) v += ((float*)Cv)[off];
                if (CB16) ((u16*)Cv)[off] = f2bh(v);
                else      ((float*)Cv)[off] = v;
                if (WDEN) p = fmaf(v, ks4[ni], p);
            }
            if (WDEN) {
                p += __shfl_xor(p, 1);
                p += __shfl_xor(p, 2);
                p += __shfl_xor(p, 4);
                p += __shfl_xor(p, 8);
                if (rl == 0) DEN[(size_t)orow * 8 + hh] = p;
            }
        }
    }
}

// ---------------- kv split-K: grid(128 bh, 4 sc), atomics into zeroed KV/KSUM ----------------
__global__ __launch_bounds__(256)
void kv_split(const u16* __restrict__ KP, const u16* __restrict__ V,
              float* __restrict__ KV, float* __restrict__ KSUM) {
    __shared__ u16 kpl[128 * 64];
    __shared__ u16 vl[128 * 64];
    int bh = blockIdx.x, sc = blockIdx.y;
    int b = bh >> 3, h = bh & 7;
    int tid = threadIdx.x;
    int d = tid & 63, mg = tid >> 6;        // 4 m-groups of 16
    float acc[16], ks[16];
    #pragma unroll
    for (int i = 0; i < 16; ++i) { acc[i] = 0.f; ks[i] = 0.f; }
    size_t rowbase = (size_t)b * Sc + sc * 512;
    for (int c = 0; c < 4; ++c) {
        __syncthreads();
        for (int i = tid; i < 1024; i += 256) {
            int row = i >> 3, c8 = (i & 7) * 8;
            size_t off = (rowbase + c * 128 + row) * Dc + h * 64 + c8;
            *reinterpret_cast<uint4*>(&kpl[row * 64 + c8]) =
                *reinterpret_cast<const uint4*>(KP + off);
            *reinterpret_cast<uint4*>(&vl[row * 64 + c8]) =
                *reinterpret_cast<const uint4*>(V + off);
        }
        __syncthreads();
        for (int s = 0; s < 128; ++s) {
            float vv = b2f(vl[s * 64 + d]);
            #pragma unroll
            for (int i = 0; i < 16; ++i) {
                float kp = b2f(kpl[s * 64 + mg * 16 + i]);
                acc[i] = fmaf(kp, vv, acc[i]);
                ks[i] += kp;
            }
        }
    }
    float* kvp = KV + (size_t)bh * 4096;
    #pragma unroll
    for (int i = 0; i < 16; ++i)
        atomicAdd(&kvp[(mg * 16 + i) * 64 + d], acc[i]);
    if (d == 0) {
        #pragma unroll
        for (int i = 0; i < 16; ++i)
            atomicAdd(&KSUM[bh * 64 + mg * 16 + i], ks[i]);
    }
}

// ---------------- num/den via MFMA: AO[r,h*64+d] = (QP[r,:].KV[b,h][:,d]) / DEN[r,h] ----------------
__global__ __launch_bounds__(256)
void numden_mfma(const u16* __restrict__ QP, const float* __restrict__ KVg,
                 const float* __restrict__ DEN, u16* __restrict__ OUT) {
    constexpr int LP = 72;
    __shared__ short Asm[128 * LP];
    __shared__ short BT[64 * LP];
    int h  = blockIdx.x;                   // 0..7
    int row0 = blockIdx.y * 128;
    int b  = row0 >> 11;
    int tid = threadIdx.x;
    int lane = tid & 63, w = tid >> 6;

    const float* kvp = KVg + ((size_t)(b * 8 + h)) * 4096;
    for (int i = tid; i < 4096; i += 256) {
        int m = i >> 6, d = i & 63;
        BT[d * LP + m] = (short)f2bh(kvp[i]);
    }
    {
        int rr = tid >> 1;
        int cc = (tid & 1) * 32;
        const u16* qp = QP + (size_t)(row0 + rr) * Dc + h * 64 + cc;
        #pragma unroll
        for (int q = 0; q < 4; ++q)
            *reinterpret_cast<uint4*>(&Asm[rr * LP + cc + q * 8]) =
                *reinterpret_cast<const uint4*>(qp + q * 8);
    }
    __syncthreads();

    int rl = lane & 15, kq = (lane >> 4) * 8;
    f32x4 acc[2][4];
    #pragma unroll
    for (int mi = 0; mi < 2; ++mi)
        #pragma unroll
        for (int ni = 0; ni < 4; ++ni) acc[mi][ni] = (f32x4){0.f, 0.f, 0.f, 0.f};
    #pragma unroll
    for (int kst = 0; kst < 2; ++kst) {
        int kg = kst * 32 + kq;
        short8 a0 = *reinterpret_cast<const short8*>(&Asm[(w * 32 + rl) * LP + kg]);
        short8 a1 = *reinterpret_cast<const short8*>(&Asm[(w * 32 + 16 + rl) * LP + kg]);
        short8 bf[4];
        #pragma unroll
        for (int ni = 0; ni < 4; ++ni)
            bf[ni] = *reinterpret_cast<const short8*>(&BT[(ni * 16 + rl) * LP + kg]);
        #pragma unroll
        for (int ni = 0; ni < 4; ++ni) {
            acc[0][ni] = __builtin_amdgcn_mfma_f32_16x16x32_bf16(a0, bf[ni], acc[0][ni], 0, 0, 0);
            acc[1][ni] = __builtin_amdgcn_mfma_f32_16x16x32_bf16(a1, bf[ni], acc[1][ni], 0, 0, 0);
        }
    }
    #pragma unroll
    for (int mi = 0; mi < 2; ++mi) {
        #pragma unroll
        for (int j = 0; j < 4; ++j) {
            int row = row0 + w * 32 + mi * 16 + (lane >> 4) * 4 + j;
            float inv = 1.f / DEN[(size_t)row * 8 + h];
            #pragma unroll
            for (int ni = 0; ni < 4; ++ni)
                OUT[(size_t)row * Dc + h * 64 + ni * 16 + rl] =
                    f2bh(acc[mi][ni][j] * inv);
        }
    }
}

// ---------------- LayerNorm over D=512, wave per row; PERM: b-major -> [S,B,D] ----------------
template <bool PERM>
__global__ __launch_bounds__(256)
void ln_kernel(const float* __restrict__ X, const float* __restrict__ Sg,
               const float* __restrict__ Bg, float* __restrict__ O) {
    int lane = threadIdx.x & 63, w = threadIdx.x >> 6;
    size_t r = (size_t)blockIdx.x * 4 + w;
    const float* xr = X + r * Dc;
    float v[8];
    *reinterpret_cast<float4*>(&v[0]) = *reinterpret_cast<const float4*>(xr + lane * 4);
    *reinterpret_cast<float4*>(&v[4]) = *reinterpret_cast<const float4*>(xr + 256 + lane * 4);
    float sum = 0.f;
    #pragma unroll
    for (int i = 0; i < 8; ++i) sum += v[i];
    #pragma unroll
    for (int off = 32; off >= 1; off >>= 1) sum += __shfl_xor(sum, off);
    float mu = sum * (1.f / Dc);
    float sq = 0.f;
    #pragma unroll
    for (int i = 0; i < 8; ++i) { float dd = v[i] - mu; sq += dd * dd; }
    #pragma unroll
    for (int off = 32; off >= 1; off >>= 1) sq += __shfl_xor(sq, off);
    float rstd = rsqrtf(sq * (1.f / Dc) + EPSc);
    float s[8], b[8];
    *reinterpret_cast<float4*>(&s[0]) = *reinterpret_cast<const float4*>(Sg + lane * 4);
    *reinterpret_cast<float4*>(&s[4]) = *reinterpret_cast<const float4*>(Sg + 256 + lane * 4);
    *reinterpret_cast<float4*>(&b[0]) = *reinterpret_cast<const float4*>(Bg + lane * 4);
    *reinterpret_cast<float4*>(&b[4]) = *reinterpret_cast<const float4*>(Bg + 256 + lane * 4);
    float o[8];
    #pragma unroll
    for (int i = 0; i < 8; ++i) o[i] = (v[i] - mu) * rstd * s[i] + b[i];
    size_t rd = PERM ? ((size_t)(r & (Sc - 1)) * Bc + (r >> 11)) : r;
    float* orow = O + rd * Dc;
    *reinterpret_cast<float4*>(orow + lane * 4) = *reinterpret_cast<const float4*>(&o[0]);
    *reinterpret_cast<float4*>(orow + 256 + lane * 4) = *reinterpret_cast<const float4*>(&o[4]);
}

// ---------------- launch ----------------
extern "C" void kernel_launch(void* const* d_in, const int* in_sizes, int n_in,
                              void* d_out, int out_size, void* d_ws, size_t ws_size,
                              hipStream_t stream) {
    (void)in_sizes; (void)n_in; (void)out_size;
    const float* src   = (const float*)d_in[0];
    const float* pos   = (const float*)d_in[2];
    const float* ipw   = (const float*)d_in[3];   // [L,1536,512]
    const float* ipb   = (const float*)d_in[4];   // [L,1536]
    const float* outw  = (const float*)d_in[5];   // [L,512,512]
    const float* outb  = (const float*)d_in[6];
    const float* l1w   = (const float*)d_in[7];   // [L,2048,512]
    const float* l1b   = (const float*)d_in[8];
    const float* l2w   = (const float*)d_in[9];   // [L,512,2048]
    const float* l2b   = (const float*)d_in[10];
    const float* n1s   = (const float*)d_in[11];
    const float* n1b   = (const float*)d_in[12];
    const float* n2s   = (const float*)d_in[13];
    const float* n2b   = (const float*)d_in[14];
    const float* worf  = (const float*)d_in[15];  // [L,64,64]
    float* out = (float*)d_out;

    const size_t RD = (size_t)Rc * Dc;            // 16,777,216 elems
    // ws: X f32 | B2 f32 | KV f32 | KSUM | DEN | WeffQ/K bf16 | beffQ/K f32
    const size_t NEED = RD * 4 + RD * 4 + (size_t)128 * 4096 * 4 + 8192 * 4
                      + (size_t)Rc * 8 * 4 + 2 * 262144 * 2 + 2 * 512 * 4;  // 138,448,896 (proven)
    if (ws_size < NEED) {
        sentinel_kernel<<<(Rc * Dc / 4 + 255) / 256, 256, 0, stream>>>(out, Rc * Dc / 4);
        return;
    }
    char* p = (char*)d_ws;
    float* X    = (float*)p;  p += RD * 4;
    float* B2f  = (float*)p;  p += RD * 4;
    float* KV   = (float*)p;  p += (size_t)128 * 4096 * 4;
    float* KSUM = (float*)p;  p += 8192 * 4;
    float* DEN  = (float*)p;  p += (size_t)Rc * 8 * 4;
    u16*  WeffQ = (u16*)p;    p += 262144 * 2;
    u16*  WeffK = (u16*)p;    p += 262144 * 2;
    float* beffQ = (float*)p; p += 512 * 4;
    float* beffK = (float*)p;

    u16*  B2u  = (u16*)B2f;           // 2*RD u16 capacity
    u16*  XPu  = B2u;                 // [R,512] bf16
    u16*  KPu  = B2u + RD;            // [R,512] bf16
    u16*  AOu  = B2u + RD;            // (KP dead by then)
    u16*  H1u  = B2u;                 // [R,2048] bf16 contiguous (XP/AO dead)
    u16*  OutU = (u16*)out;
    u16*  Vu   = OutU;                // [R,512] bf16
    u16*  QPu  = OutU + RD;           // [R,512] bf16
    float* T1f = out;                 // f32 [R,512] (V/QP dead)
    u16*  XBu  = OutU;                // bf16 twin of LN1(x) (T1f dead after ln1)

    dim3 blk(256);
    dim3 g512(4, Rc / 128);
    dim3 g2048(16, Rc / 128);
    const int nz4 = (128 * 4096 + 8192) / 4;   // KV+KSUM contiguous

    for (int i = 0; i < Lc; ++i) {
        const float* w_qkv = ipw + (size_t)i * 1536 * 512;
        const float* b_qkv = ipb + (size_t)i * 1536;
        const float* w_v  = w_qkv + (size_t)1024 * 512;
        const float* b_v  = b_qkv + 1024;
        const float* w_o  = outw + (size_t)i * 512 * 512;
        const float* b_o  = outb + (size_t)i * 512;
        const float* w_1  = l1w + (size_t)i * 2048 * 512;
        const float* b_1  = l1b + (size_t)i * 2048;
        const float* w_2  = l2w + (size_t)i * 512 * 2048;
        const float* b_2  = l2b + (size_t)i * 512;
        const float* wo_i = worf + (size_t)i * 4096;

        weff_kernel<<<dim3(8, 8), blk, 0, stream>>>(
            w_qkv, b_qkv, wo_i, WeffQ, WeffK, beffQ, beffK);

        if (i == 0)
            hipMemcpyAsync(X, src, RD * 4, hipMemcpyDeviceToDevice, stream);

        // XP = bf16(X + pos)
        xp_kernel<<<(int)(RD / 8 / 256), blk, 0, stream>>>(X, pos, XPu);
        // KP = relu(XP @ WeffK^T + beffK) + STAB -> bf16
        gemm_mfma<4, true, true, false><<<g512, blk, 0, stream>>>(
            XPu, 512, WeffK, 512, beffK, nullptr, KPu, 512, 512, nullptr, nullptr);
        // V = X @ Wv^T + bv -> bf16
        gemm_mfma<0, false, false, false><<<g512, blk, 0, stream>>>(
            X, 512, w_v, 512, b_v, nullptr, Vu, 512, 512, nullptr, nullptr);
        // zero KV+KSUM, then kv split-K
        zero_kernel<<<(nz4 + 255) / 256, blk, 0, stream>>>(KV, nz4);
        kv_split<<<dim3(128, 4), blk, 0, stream>>>(KPu, Vu, KV, KSUM);
        // QP (+DEN) -> bf16
        gemm_mfma<4, true, true, true><<<g512, blk, 0, stream>>>(
            XPu, 512, WeffQ, 512, beffQ, nullptr, QPu, 512, 512, KSUM, DEN);
        // AO = num/den -> bf16 (KP region dead)
        numden_mfma<<<dim3(8, Rc / 128), blk, 0, stream>>>(QPu, KV, DEN, AOu);
        // T1 = X + AO @ Wo^T + bo -> f32 in d_out (V/QP dead)
        gemm_mfma<2, true, false, false><<<g512, blk, 0, stream>>>(
            AOu, 512, w_o, 512, b_o, X, T1f, 512, 512, nullptr, nullptr);
        // x = LN(T1) -> X
        ln_kernel<false><<<Rc / 4, blk, 0, stream>>>(T1f, n1s + i * 512, n1b + i * 512, X);
        // XB = bf16(X)  (T1f dead; lives in d_out lower half)
        xb_kernel<<<(int)(RD / 8 / 256), blk, 0, stream>>>(X, XBu);
        // FFN1: H1 = relu(XB @ W1^T + b1) bf16, ONE N=2048 dispatch -> B2 (XP/AO dead)
        gemm_mfma<1, true, false, false><<<g2048, blk, 0, stream>>>(
            XBu, 512, w_1, 512, b_1, nullptr, H1u, 2048, 512, nullptr, nullptr);
        // FFN2 fused: X = X + H1 @ W2^T + b2  (ONE K=2048 dispatch, contiguous H1)
        gemm_mfma<2, true, false, false><<<g512, blk, 0, stream>>>(
            H1u, 2048, w_2, 2048, b_2, X, X, 512, 2048, nullptr, nullptr);
        // x = LN(T2=X); final layer permutes b-major -> [S,B,D] into d_out
        if (i == Lc - 1)
            ln_kernel<true><<<Rc / 4, blk, 0, stream>>>(X, n2s + i * 512, n2b + i * 512, out);
        else
            ln_kernel<false><<<Rc / 4, blk, 0, stream>>>(X, n2s + i * 512, n2b + i * 512, X);
    }
}

// Round 14
// 4018.721 us; speedup vs baseline: 1.0949x; 1.0339x over previous
//
#include <hip/hip_runtime.h>

typedef unsigned short u16;
typedef unsigned int   u32;
typedef __attribute__((ext_vector_type(8))) short short8;
typedef __attribute__((ext_vector_type(4))) float f32x4;

// ---------------- constants ----------------
constexpr int Dc   = 512;
constexpr int Lc   = 6;
constexpr int Bc   = 16;
constexpr int Sc   = 2048;
constexpr int Rc   = Sc * Bc;                 // 32768 rows (b-major: r = b*S + s)
constexpr float RATIO = 0.3535533905932738f;  // 1/64^0.25
constexpr float STABc = 1e-3f;
constexpr float EPSc  = 1e-5f;

// f32 pair -> packed 2x bf16 (RNE)
__device__ __forceinline__ u32 pk2(float lo, float hi) {
    u32 a = __float_as_uint(lo), b = __float_as_uint(hi);
    a = (a + 0x7FFFu + ((a >> 16) & 1u)) >> 16;
    b = (b + 0x7FFFu + ((b >> 16) & 1u)) & 0xFFFF0000u;
    return a | b;
}
__device__ __forceinline__ u16 f2bh(float f) {
    u32 u = __float_as_uint(f);
    return (u16)((u + 0x7FFFu + ((u >> 16) & 1u)) >> 16);
}
__device__ __forceinline__ float b2f(u16 u) { return __uint_as_float(((u32)u) << 16); }

// ---------------- sentinel (ws too small diagnostic) ----------------
__global__ __launch_bounds__(256)
void sentinel_kernel(float* O, int n4) {
    int i = blockIdx.x * 256 + threadIdx.x;
    if (i < n4) {
        float4 v = make_float4(12345.f, 12345.f, 12345.f, 12345.f);
        *reinterpret_cast<float4*>(O + (size_t)i * 4) = v;
    }
}

// ---------------- zero KV/KSUM ----------------
__global__ __launch_bounds__(256)
void zero_kernel(float* p, int n4) {
    int i = blockIdx.x * 256 + threadIdx.x;
    if (i < n4) {
        float4 z = make_float4(0.f, 0.f, 0.f, 0.f);
        *reinterpret_cast<float4*>(p + (size_t)i * 4) = z;
    }
}

// ---------------- XP = bf16(X + pos)  (bootstrap, b-major: pos is linear) ----------------
__global__ __launch_bounds__(256)
void xp_kernel(const float* __restrict__ X, const float* __restrict__ POS,
               u16* __restrict__ XP) {
    size_t i = (size_t)blockIdx.x * 256 + threadIdx.x;   // 8-elem chunk
    size_t base = i * 8;
    float4 x0 = *reinterpret_cast<const float4*>(X + base);
    float4 x1 = *reinterpret_cast<const float4*>(X + base + 4);
    float4 p0 = *reinterpret_cast<const float4*>(POS + base);
    float4 p1 = *reinterpret_cast<const float4*>(POS + base + 4);
    uint4 o;
    o.x = pk2(x0.x + p0.x, x0.y + p0.y);
    o.y = pk2(x0.z + p0.z, x0.w + p0.w);
    o.z = pk2(x1.x + p1.x, x1.y + p1.y);
    o.w = pk2(x1.z + p1.z, x1.w + p1.w);
    *reinterpret_cast<uint4*>(XP + base) = o;
}

// ---------------- XB = bf16(X)  (twin for bf16-A GEMMs) ----------------
__global__ __launch_bounds__(256)
void xb_kernel(const float* __restrict__ X, u16* __restrict__ XB) {
    size_t i = (size_t)blockIdx.x * 256 + threadIdx.x;   // 8-elem chunk
    size_t base = i * 8;
    float4 x0 = *reinterpret_cast<const float4*>(X + base);
    float4 x1 = *reinterpret_cast<const float4*>(X + base + 4);
    uint4 o;
    o.x = pk2(x0.x, x0.y); o.y = pk2(x0.z, x0.w);
    o.z = pk2(x1.x, x1.y); o.w = pk2(x1.z, x1.w);
    *reinterpret_cast<uint4*>(XB + base) = o;
}

// ---------------- Weff precompute (ORF folded; weights bf16, bias f32) ----------------
__global__ __launch_bounds__(256)
void weff_kernel(const float* __restrict__ Wqkv, const float* __restrict__ bqkv,
                 const float* __restrict__ worf,
                 u16* __restrict__ WeffQ, u16* __restrict__ WeffK,
                 float* __restrict__ beffQ, float* __restrict__ beffK) {
    __shared__ float wl[64][64];
    __shared__ float ql[64][68];
    __shared__ float kl[64][68];
    int cc = blockIdx.x, h = blockIdx.y;
    int tid = threadIdx.x;
    for (int i = tid; i < 4096; i += 256) wl[i >> 6][i & 63] = worf[i];
    for (int i = tid; i < 4096; i += 256) {
        int d = i >> 6, c = i & 63;
        ql[d][c] = Wqkv[(size_t)(h * 64 + d) * 512 + cc * 64 + c];
        kl[d][c] = Wqkv[(size_t)(512 + h * 64 + d) * 512 + cc * 64 + c];
    }
    __syncthreads();
    int m = tid >> 2, c0 = (tid & 3) * 16;
    float acc[16];
    #pragma unroll
    for (int j = 0; j < 16; ++j) acc[j] = 0.f;
    for (int d = 0; d < 64; ++d) {
        float wv = wl[m][d];
        #pragma unroll
        for (int j = 0; j < 16; ++j) acc[j] = fmaf(wv, ql[d][c0 + j], acc[j]);
    }
    for (int j = 0; j < 16; ++j)
        WeffQ[(size_t)(h * 64 + m) * 512 + cc * 64 + c0 + j] = f2bh(RATIO * acc[j]);
    #pragma unroll
    for (int j = 0; j < 16; ++j) acc[j] = 0.f;
    for (int d = 0; d < 64; ++d) {
        float wv = wl[m][d];
        #pragma unroll
        for (int j = 0; j < 16; ++j) acc[j] = fmaf(wv, kl[d][c0 + j], acc[j]);
    }
    for (int j = 0; j < 16; ++j)
        WeffK[(size_t)(h * 64 + m) * 512 + cc * 64 + c0 + j] = f2bh(RATIO * acc[j]);
    if (cc == 0 && tid < 64) {
        float bq = 0.f, bk = 0.f;
        for (int d = 0; d < 64; ++d) {
            bq = fmaf(wl[tid][d], bqkv[h * 64 + d], bq);
            bk = fmaf(wl[tid][d], bqkv[512 + h * 64 + d], bk);
        }
        beffQ[h * 64 + tid] = RATIO * bq;
        beffK[h * 64 + tid] = RATIO * bk;
    }
}

// ---------------- MFMA GEMM (round-7 proven core): C[r,n] = op( sum_k A[r,k]*W[n,k] ) ----------------
// 128x128 tile, 4 waves (2x2 of 64x64), BK=32, LDS row stride 40 shorts.
// A bf16 (ABF16) or f32 (converted during staging). W bf16 (WBF16) or f32.
// MODE 0:+bias->bf16  1:relu->bf16  4:relu+STAB->bf16  2:+bias+res(f32)->f32  3:C+=acc(f32)
template <int MODE, bool ABF16, bool WBF16>
__global__ __launch_bounds__(256)
void gemm_mfma(const void* __restrict__ Av, int lda,
               const void* __restrict__ Wv, int ldw,
               const float* __restrict__ bias, const float* __restrict__ res,
               void* __restrict__ Cv, int ldc, int K) {
    constexpr int LP = 40;
    constexpr bool CB16 = (MODE == 0 || MODE == 1 || MODE == 4);
    __shared__ short As[128 * LP];
    __shared__ short Bs[128 * LP];
    int tid = threadIdx.x;
    int lane = tid & 63, wv = tid >> 6;
    int wr = wv >> 1, wc = wv & 1;
    int row0 = blockIdx.y * 128, col0 = blockIdx.x * 128;

    int srow = tid >> 1;
    int sks  = (tid & 1) << 4;              // 0 or 16
    int arow = row0 + srow;

    f32x4 acc[4][4];
    #pragma unroll
    for (int mi = 0; mi < 4; ++mi)
        #pragma unroll
        for (int ni = 0; ni < 4; ++ni)
            acc[mi][ni] = (f32x4){0.f, 0.f, 0.f, 0.f};

    int rl = lane & 15;
    int kg = (lane >> 4) * 8;

    for (int k0 = 0; k0 < K; k0 += 32) {
        uint4 qa0, qa1, qb0, qb1;
        if (ABF16) {
            const u16* Ap = (const u16*)Av + (size_t)arow * lda + sks;
            qa0 = *reinterpret_cast<const uint4*>(Ap + k0);
            qa1 = *reinterpret_cast<const uint4*>(Ap + k0 + 8);
        } else {
            const float* Ap = (const float*)Av + (size_t)arow * lda + sks;
            float4 a0 = *reinterpret_cast<const float4*>(Ap + k0);
            float4 a1 = *reinterpret_cast<const float4*>(Ap + k0 + 4);
            float4 a2 = *reinterpret_cast<const float4*>(Ap + k0 + 8);
            float4 a3 = *reinterpret_cast<const float4*>(Ap + k0 + 12);
            qa0.x = pk2(a0.x, a0.y); qa0.y = pk2(a0.z, a0.w);
            qa0.z = pk2(a1.x, a1.y); qa0.w = pk2(a1.z, a1.w);
            qa1.x = pk2(a2.x, a2.y); qa1.y = pk2(a2.z, a2.w);
            qa1.z = pk2(a3.x, a3.y); qa1.w = pk2(a3.z, a3.w);
        }
        if (WBF16) {
            const u16* Wp = (const u16*)Wv + (size_t)(col0 + srow) * ldw + sks;
            qb0 = *reinterpret_cast<const uint4*>(Wp + k0);
            qb1 = *reinterpret_cast<const uint4*>(Wp + k0 + 8);
        } else {
            const float* Wp = (const float*)Wv + (size_t)(col0 + srow) * ldw + sks;
            float4 b0 = *reinterpret_cast<const float4*>(Wp + k0);
            float4 b1 = *reinterpret_cast<const float4*>(Wp + k0 + 4);
            float4 b2 = *reinterpret_cast<const float4*>(Wp + k0 + 8);
            float4 b3 = *reinterpret_cast<const float4*>(Wp + k0 + 12);
            qb0.x = pk2(b0.x, b0.y); qb0.y = pk2(b0.z, b0.w);
            qb0.z = pk2(b1.x, b1.y); qb0.w = pk2(b1.z, b1.w);
            qb1.x = pk2(b2.x, b2.y); qb1.y = pk2(b2.z, b2.w);
            qb1.z = pk2(b3.x, b3.y); qb1.w = pk2(b3.z, b3.w);
        }
        __syncthreads();
        *reinterpret_cast<uint4*>(&As[srow * LP + sks])     = qa0;
        *reinterpret_cast<uint4*>(&As[srow * LP + sks + 8]) = qa1;
        *reinterpret_cast<uint4*>(&Bs[srow * LP + sks])     = qb0;
        *reinterpret_cast<uint4*>(&Bs[srow * LP + sks + 8]) = qb1;
        __syncthreads();
        short8 af[4], bf[4];
        #pragma unroll
        for (int mi = 0; mi < 4; ++mi)
            af[mi] = *reinterpret_cast<const short8*>(&As[(wr * 64 + mi * 16 + rl) * LP + kg]);
        #pragma unroll
        for (int ni = 0; ni < 4; ++ni)
            bf[ni] = *reinterpret_cast<const short8*>(&Bs[(wc * 64 + ni * 16 + rl) * LP + kg]);
        #pragma unroll
        for (int mi = 0; mi < 4; ++mi)
            #pragma unroll
            for (int ni = 0; ni < 4; ++ni)
                acc[mi][ni] = __builtin_amdgcn_mfma_f32_16x16x32_bf16(
                    af[mi], bf[ni], acc[mi][ni], 0, 0, 0);
    }

    int orb = row0 + wr * 64 + (lane >> 4) * 4;
    int ocb = col0 + wc * 64 + rl;
    float bv[4];
    #pragma unroll
    for (int ni = 0; ni < 4; ++ni)
        bv[ni] = (MODE != 3) ? bias[ocb + ni * 16] : 0.f;
    #pragma unroll
    for (int mi = 0; mi < 4; ++mi) {
        #pragma unroll
        for (int j = 0; j < 4; ++j) {
            int orow = orb + mi * 16 + j;
            size_t base = (size_t)orow * ldc + ocb;
            #pragma unroll
            for (int ni = 0; ni < 4; ++ni) {
                float v = acc[mi][ni][j] + bv[ni];
                if (MODE == 1) v = fmaxf(v, 0.f);
                if (MODE == 4) v = fmaxf(v, 0.f) + STABc;
                size_t off = base + ni * 16;
                if (MODE == 2) v += res[off];
                if (MODE == 3) v += ((float*)Cv)[off];
                if (CB16) ((u16*)Cv)[off] = f2bh(v);
                else      ((float*)Cv)[off] = v;
            }
        }
    }
}

// ---------------- kv split-K: grid(128 bh, 4 sc); KP strided 1024 (in KQP), V 512 ----------------
__global__ __launch_bounds__(256)
void kv_split(const u16* __restrict__ KQP, const u16* __restrict__ V,
              float* __restrict__ KV, float* __restrict__ KSUM) {
    __shared__ u16 kpl[128 * 64];
    __shared__ u16 vl[128 * 64];
    int bh = blockIdx.x, sc = blockIdx.y;
    int b = bh >> 3, h = bh & 7;
    int tid = threadIdx.x;
    int d = tid & 63, mg = tid >> 6;        // 4 m-groups of 16
    float acc[16], ks[16];
    #pragma unroll
    for (int i = 0; i < 16; ++i) { acc[i] = 0.f; ks[i] = 0.f; }
    size_t rowbase = (size_t)b * Sc + sc * 512;
    for (int c = 0; c < 4; ++c) {
        __syncthreads();
        for (int i = tid; i < 1024; i += 256) {
            int row = i >> 3, c8 = (i & 7) * 8;
            size_t r = rowbase + c * 128 + row;
            *reinterpret_cast<uint4*>(&kpl[row * 64 + c8]) =
                *reinterpret_cast<const uint4*>(KQP + r * 1024 + h * 64 + c8);
            *reinterpret_cast<uint4*>(&vl[row * 64 + c8]) =
                *reinterpret_cast<const uint4*>(V + r * 512 + h * 64 + c8);
        }
        __syncthreads();
        for (int s = 0; s < 128; ++s) {
            float vv = b2f(vl[s * 64 + d]);
            #pragma unroll
            for (int i = 0; i < 16; ++i) {
                float kp = b2f(kpl[s * 64 + mg * 16 + i]);
                acc[i] = fmaf(kp, vv, acc[i]);
                ks[i] += kp;
            }
        }
    }
    float* kvp = KV + (size_t)bh * 4096;
    #pragma unroll
    for (int i = 0; i < 16; ++i)
        atomicAdd(&kvp[(mg * 16 + i) * 64 + d], acc[i]);
    if (d == 0) {
        #pragma unroll
        for (int i = 0; i < 16; ++i)
            atomicAdd(&KSUM[bh * 64 + mg * 16 + i], ks[i]);
    }
}

// ---------------- num/den via MFMA: QP from KQP (stride 1024, +512); den from bf16 QP ----------------
__global__ __launch_bounds__(256)
void numden_mfma(const u16* __restrict__ KQP, const float* __restrict__ KVg,
                 const float* __restrict__ KSUM, u16* __restrict__ OUT) {
    constexpr int LP = 72;
    __shared__ short Asm[128 * LP];
    __shared__ short BT[64 * LP];
    __shared__ float ksl[64];
    __shared__ float dsm[128][2];
    int h  = blockIdx.x;                   // 0..7
    int row0 = blockIdx.y * 128;
    int b  = row0 >> 11;
    int tid = threadIdx.x;
    int lane = tid & 63, w = tid >> 6;

    const float* kvp = KVg + ((size_t)(b * 8 + h)) * 4096;
    for (int i = tid; i < 4096; i += 256) {
        int m = i >> 6, d = i & 63;
        BT[d * LP + m] = (short)f2bh(kvp[i]);
    }
    if (tid < 64) ksl[tid] = KSUM[(b * 8 + h) * 64 + tid];
    {
        int rr = tid >> 1;
        int cc = (tid & 1) * 32;
        const u16* qp = KQP + (size_t)(row0 + rr) * 1024 + 512 + h * 64 + cc;
        #pragma unroll
        for (int q = 0; q < 4; ++q)
            *reinterpret_cast<uint4*>(&Asm[rr * LP + cc + q * 8]) =
                *reinterpret_cast<const uint4*>(qp + q * 8);
    }
    __syncthreads();

    // den[row] = sum_m qp_bf16[row,m] * ksum[m]  (two half-sums per row)
    {
        int rr = tid >> 1, half = tid & 1;
        const short* ap = &Asm[rr * LP + half * 32];
        float pden = 0.f;
        #pragma unroll
        for (int m = 0; m < 32; ++m)
            pden = fmaf(b2f((u16)ap[m]), ksl[half * 32 + m], pden);
        dsm[rr][half] = pden;
    }
    __syncthreads();

    int rl = lane & 15, kq = (lane >> 4) * 8;
    f32x4 acc[2][4];
    #pragma unroll
    for (int mi = 0; mi < 2; ++mi)
        #pragma unroll
        for (int ni = 0; ni < 4; ++ni) acc[mi][ni] = (f32x4){0.f, 0.f, 0.f, 0.f};
    #pragma unroll
    for (int kst = 0; kst < 2; ++kst) {
        int kg = kst * 32 + kq;
        short8 a0 = *reinterpret_cast<const short8*>(&Asm[(w * 32 + rl) * LP + kg]);
        short8 a1 = *reinterpret_cast<const short8*>(&Asm[(w * 32 + 16 + rl) * LP + kg]);
        short8 bf[4];
        #pragma unroll
        for (int ni = 0; ni < 4; ++ni)
            bf[ni] = *reinterpret_cast<const short8*>(&BT[(ni * 16 + rl) * LP + kg]);
        #pragma unroll
        for (int ni = 0; ni < 4; ++ni) {
            acc[0][ni] = __builtin_amdgcn_mfma_f32_16x16x32_bf16(a0, bf[ni], acc[0][ni], 0, 0, 0);
            acc[1][ni] = __builtin_amdgcn_mfma_f32_16x16x32_bf16(a1, bf[ni], acc[1][ni], 0, 0, 0);
        }
    }
    #pragma unroll
    for (int mi = 0; mi < 2; ++mi) {
        #pragma unroll
        for (int j = 0; j < 4; ++j) {
            int lr = w * 32 + mi * 16 + (lane >> 4) * 4 + j;
            int row = row0 + lr;
            float inv = 1.f / (dsm[lr][0] + dsm[lr][1]);
            #pragma unroll
            for (int ni = 0; ni < 4; ++ni)
                OUT[(size_t)row * Dc + h * 64 + ni * 16 + rl] =
                    f2bh(acc[mi][ni][j] * inv);
        }
    }
}

// ---------------- LayerNorm, wave per row; PERM: b-major -> [S,B,D] output ----------------
template <bool PERM>
__global__ __launch_bounds__(256)
void ln_kernel(const float* __restrict__ X, const float* __restrict__ Sg,
               const float* __restrict__ Bg, float* __restrict__ O) {
    int lane = threadIdx.x & 63, w = threadIdx.x >> 6;
    size_t r = (size_t)blockIdx.x * 4 + w;
    const float* xr = X + r * Dc;
    float v[8];
    *reinterpret_cast<float4*>(&v[0]) = *reinterpret_cast<const float4*>(xr + lane * 4);
    *reinterpret_cast<float4*>(&v[4]) = *reinterpret_cast<const float4*>(xr + 256 + lane * 4);
    float sum = 0.f;
    #pragma unroll
    for (int i = 0; i < 8; ++i) sum += v[i];
    #pragma unroll
    for (int off = 32; off >= 1; off >>= 1) sum += __shfl_xor(sum, off);
    float mu = sum * (1.f / Dc);
    float sq = 0.f;
    #pragma unroll
    for (int i = 0; i < 8; ++i) { float dd = v[i] - mu; sq += dd * dd; }
    #pragma unroll
    for (int off = 32; off >= 1; off >>= 1) sq += __shfl_xor(sq, off);
    float rstd = rsqrtf(sq * (1.f / Dc) + EPSc);
    float s[8], b[8];
    *reinterpret_cast<float4*>(&s[0]) = *reinterpret_cast<const float4*>(Sg + lane * 4);
    *reinterpret_cast<float4*>(&s[4]) = *reinterpret_cast<const float4*>(Sg + 256 + lane * 4);
    *reinterpret_cast<float4*>(&b[0]) = *reinterpret_cast<const float4*>(Bg + lane * 4);
    *reinterpret_cast<float4*>(&b[4]) = *reinterpret_cast<const float4*>(Bg + 256 + lane * 4);
    float o[8];
    #pragma unroll
    for (int i = 0; i < 8; ++i) o[i] = (v[i] - mu) * rstd * s[i] + b[i];
    size_t rd = PERM ? ((size_t)(r & (Sc - 1)) * Bc + (r >> 11)) : r;
    float* orow = O + rd * Dc;
    *reinterpret_cast<float4*>(orow + lane * 4) = *reinterpret_cast<const float4*>(&o[0]);
    *reinterpret_cast<float4*>(orow + 256 + lane * 4) = *reinterpret_cast<const float4*>(&o[4]);
}

// ---------------- ln2 fused: X=LN(X) in-place, XP=bf16(x+pos), XB=bf16(x) ----------------
__global__ __launch_bounds__(256)
void ln2f_kernel(float* __restrict__ X, const float* __restrict__ Sg,
                 const float* __restrict__ Bg, const float* __restrict__ POS,
                 u16* __restrict__ XP, u16* __restrict__ XB) {
    int lane = threadIdx.x & 63, w = threadIdx.x >> 6;
    size_t r = (size_t)blockIdx.x * 4 + w;
    float* xr = X + r * Dc;
    float v[8];
    *reinterpret_cast<float4*>(&v[0]) = *reinterpret_cast<const float4*>(xr + lane * 4);
    *reinterpret_cast<float4*>(&v[4]) = *reinterpret_cast<const float4*>(xr + 256 + lane * 4);
    float sum = 0.f;
    #pragma unroll
    for (int i = 0; i < 8; ++i) sum += v[i];
    #pragma unroll
    for (int off = 32; off >= 1; off >>= 1) sum += __shfl_xor(sum, off);
    float mu = sum * (1.f / Dc);
    float sq = 0.f;
    #pragma unroll
    for (int i = 0; i < 8; ++i) { float dd = v[i] - mu; sq += dd * dd; }
    #pragma unroll
    for (int off = 32; off >= 1; off >>= 1) sq += __shfl_xor(sq, off);
    float rstd = rsqrtf(sq * (1.f / Dc) + EPSc);
    float s[8], b[8];
    *reinterpret_cast<float4*>(&s[0]) = *reinterpret_cast<const float4*>(Sg + lane * 4);
    *reinterpret_cast<float4*>(&s[4]) = *reinterpret_cast<const float4*>(Sg + 256 + lane * 4);
    *reinterpret_cast<float4*>(&b[0]) = *reinterpret_cast<const float4*>(Bg + lane * 4);
    *reinterpret_cast<float4*>(&b[4]) = *reinterpret_cast<const float4*>(Bg + 256 + lane * 4);
    float p[8];
    *reinterpret_cast<float4*>(&p[0]) = *reinterpret_cast<const float4*>(POS + r * Dc + lane * 4);
    *reinterpret_cast<float4*>(&p[4]) = *reinterpret_cast<const float4*>(POS + r * Dc + 256 + lane * 4);
    float o[8];
    #pragma unroll
    for (int i = 0; i < 8; ++i) o[i] = (v[i] - mu) * rstd * s[i] + b[i];
    *reinterpret_cast<float4*>(xr + lane * 4)       = *reinterpret_cast<const float4*>(&o[0]);
    *reinterpret_cast<float4*>(xr + 256 + lane * 4) = *reinterpret_cast<const float4*>(&o[4]);
    uint2 xb0, xb1, xp0, xp1;
    xb0.x = pk2(o[0], o[1]); xb0.y = pk2(o[2], o[3]);
    xb1.x = pk2(o[4], o[5]); xb1.y = pk2(o[6], o[7]);
    xp0.x = pk2(o[0] + p[0], o[1] + p[1]); xp0.y = pk2(o[2] + p[2], o[3] + p[3]);
    xp1.x = pk2(o[4] + p[4], o[5] + p[5]); xp1.y = pk2(o[6] + p[6], o[7] + p[7]);
    *reinterpret_cast<uint2*>(XB + r * Dc + lane * 4)       = xb0;
    *reinterpret_cast<uint2*>(XB + r * Dc + 256 + lane * 4) = xb1;
    *reinterpret_cast<uint2*>(XP + r * Dc + lane * 4)       = xp0;
    *reinterpret_cast<uint2*>(XP + r * Dc + 256 + lane * 4) = xp1;
}

// ---------------- launch ----------------
extern "C" void kernel_launch(void* const* d_in, const int* in_sizes, int n_in,
                              void* d_out, int out_size, void* d_ws, size_t ws_size,
                              hipStream_t stream) {
    (void)in_sizes; (void)n_in; (void)out_size;
    const float* src   = (const float*)d_in[0];
    const float* pos   = (const float*)d_in[2];
    const float* ipw   = (const float*)d_in[3];   // [L,1536,512]
    const float* ipb   = (const float*)d_in[4];   // [L,1536]
    const float* outw  = (const float*)d_in[5];   // [L,512,512]
    const float* outb  = (const float*)d_in[6];
    const float* l1w   = (const float*)d_in[7];   // [L,2048,512]
    const float* l1b   = (const float*)d_in[8];
    const float* l2w   = (const float*)d_in[9];   // [L,512,2048]
    const float* l2b   = (const float*)d_in[10];
    const float* n1s   = (const float*)d_in[11];
    const float* n1b   = (const float*)d_in[12];
    const float* n2s   = (const float*)d_in[13];
    const float* n2b   = (const float*)d_in[14];
    const float* worf  = (const float*)d_in[15];  // [L,64,64]
    float* out = (float*)d_out;

    const size_t RD = (size_t)Rc * Dc;            // 16,777,216 elems
    // ws: X f32 | B2 f32 | KV f32 | KSUM | DEN(unused) | WeffKQ bf16 | beffKQ f32   (layout = r12, proven)
    const size_t NEED = RD * 4 + RD * 4 + (size_t)128 * 4096 * 4 + 8192 * 4
                      + (size_t)Rc * 8 * 4 + 2 * 262144 * 2 + 2 * 512 * 4;  // 138,448,896 (proven)
    if (ws_size < NEED) {
        sentinel_kernel<<<(Rc * Dc / 4 + 255) / 256, 256, 0, stream>>>(out, Rc * Dc / 4);
        return;
    }
    char* p = (char*)d_ws;
    float* X    = (float*)p;  p += RD * 4;
    float* B2f  = (float*)p;  p += RD * 4;
    float* KV   = (float*)p;  p += (size_t)128 * 4096 * 4;
    float* KSUM = (float*)p;  p += 8192 * 4;
    p += (size_t)Rc * 8 * 4;                      // DEN region (unused, layout stability)
    u16*  WeffKQ = (u16*)p;   p += 2 * 262144 * 2;   // [1024,512]: rows 0-511 K, 512-1023 Q
    float* beffKQ = (float*)p;                       // [1024]: 0-511 K, 512-1023 Q

    u16*  B2u  = (u16*)B2f;           // 2*RD u16 capacity
    u16*  XPu  = B2u;                 // [R,512] bf16(x+pos), from ln2f / bootstrap
    u16*  Vu   = B2u + RD;            // [R,512] bf16 V
    u16*  AOu  = B2u + RD;            // AO after kv (Vu dead)
    u16*  H1u  = B2u;                 // [R,2048] bf16 (XPu/AOu dead)
    u16*  OutU = (u16*)out;
    u16*  XB2u = OutU;                // lower: bf16(x) for V-GEMM (from prev ln2f)
    u16*  KQPu = OutU;                // full [R,1024]: cols 0-511 KP, 512-1023 QP
    float* T1f = out;                 // f32 [R,512] (KQP dead)
    u16*  XBu  = OutU;                // lower: bf16(ln1 x) for FFN1 (T1f dead)

    dim3 blk(256);
    dim3 g512(4, Rc / 128);
    dim3 g1024(8, Rc / 128);
    dim3 g2048(16, Rc / 128);
    const int nz4 = (128 * 4096 + 8192) / 4;   // KV+KSUM contiguous

    for (int i = 0; i < Lc; ++i) {
        const float* w_qkv = ipw + (size_t)i * 1536 * 512;
        const float* b_qkv = ipb + (size_t)i * 1536;
        const float* w_v  = w_qkv + (size_t)1024 * 512;
        const float* b_v  = b_qkv + 1024;
        const float* w_o  = outw + (size_t)i * 512 * 512;
        const float* b_o  = outb + (size_t)i * 512;
        const float* w_1  = l1w + (size_t)i * 2048 * 512;
        const float* b_1  = l1b + (size_t)i * 2048;
        const float* w_2  = l2w + (size_t)i * 512 * 2048;
        const float* b_2  = l2b + (size_t)i * 512;
        const float* wo_i = worf + (size_t)i * 4096;

        // stacked [K;Q] effective weights: K half at base, Q half at +262144 / +512
        weff_kernel<<<dim3(8, 8), blk, 0, stream>>>(
            w_qkv, b_qkv, wo_i, WeffKQ + 262144, WeffKQ, beffKQ + 512, beffKQ);

        if (i == 0) {
            hipMemcpyAsync(X, src, RD * 4, hipMemcpyDeviceToDevice, stream);
            xb_kernel<<<(int)(RD / 8 / 256), blk, 0, stream>>>(X, XB2u);
            xp_kernel<<<(int)(RD / 8 / 256), blk, 0, stream>>>(X, pos, XPu);
        }

        // V = XB2 @ Wv^T + bv -> Vu (B2 upper); A bf16 (reads d_out lower)
        gemm_mfma<0, true, false><<<g512, blk, 0, stream>>>(
            XB2u, 512, w_v, 512, b_v, nullptr, Vu, 512, 512);
        // [KP|QP] = relu(XP @ WeffKQ^T + beffKQ) + STAB -> KQP (d_out full, ldc=1024)
        gemm_mfma<4, true, true><<<g1024, blk, 0, stream>>>(
            XPu, 512, WeffKQ, 512, beffKQ, nullptr, KQPu, 1024, 512);
        // zero KV+KSUM, then kv split-K (KP strided 1024)
        zero_kernel<<<(nz4 + 255) / 256, blk, 0, stream>>>(KV, nz4);
        kv_split<<<dim3(128, 4), blk, 0, stream>>>(KQPu, Vu, KV, KSUM);
        // AO = num/den -> AOu (B2 upper; Vu dead); den computed in-kernel
        numden_mfma<<<dim3(8, Rc / 128), blk, 0, stream>>>(KQPu, KV, KSUM, AOu);
        // T1 = X + AO @ Wo^T + bo -> f32 in d_out (KQP dead)
        gemm_mfma<2, true, false><<<g512, blk, 0, stream>>>(
            AOu, 512, w_o, 512, b_o, X, T1f, 512, 512);
        // x = LN(T1) -> X
        ln_kernel<false><<<Rc / 4, blk, 0, stream>>>(T1f, n1s + i * 512, n1b + i * 512, X);
        // XB = bf16(X) (d_out lower; T1f dead)
        xb_kernel<<<(int)(RD / 8 / 256), blk, 0, stream>>>(X, XBu);
        // FFN1: H1 = relu(XB @ W1^T + b1) bf16 -> B2 full (XPu/AOu dead)
        gemm_mfma<1, true, false><<<g2048, blk, 0, stream>>>(
            XBu, 512, w_1, 512, b_1, nullptr, H1u, 2048, 512);
        // FFN2 fused: X = X + H1 @ W2^T + b2  (K=2048, in-place f32)
        gemm_mfma<2, true, false><<<g512, blk, 0, stream>>>(
            H1u, 2048, w_2, 2048, b_2, X, X, 512, 2048);
        // ln2: last layer -> permuted d_out; else fused (X, XP, XB2 for next layer)
        if (i == Lc - 1)
            ln_kernel<true><<<Rc / 4, blk, 0, stream>>>(X, n2s + i * 512, n2b + i * 512, out);
        else
            ln2f_kernel<<<Rc / 4, blk, 0, stream>>>(X, n2s + i * 512, n2b + i * 512,
                                                    pos, XPu, XB2u);
    }
}